// Round 1
// baseline (647.484 us; speedup 1.0000x reference)
//
#include <hip/hip_runtime.h>
#include <cstdint>
#include <cstddef>

#define NN 2048
#define LL 2
#define HH 4
#define DD 16
#define FF 64
#define CC 32
#define EE 64
#define ML (NN*LL)          // 4096

// ---------------- kernel 0: unique component ids ----------------
__global__ __launch_bounds__(256) void k_unique(const int* __restrict__ comp,
                                                int* __restrict__ presence,
                                                int* __restrict__ unique_out,
                                                float* __restrict__ uniq_f_out)
{
    int t = threadIdx.x;
    if (t < 64) presence[t] = 0;
    __syncthreads();
    for (int n = t; n < NN; n += 256) {
        int v = comp[n];
        if (v >= 0 && v < 64) presence[v] = 1;
    }
    __syncthreads();
    if (t < 64) {
        int rank = 0;
        for (int u = 0; u < t; ++u) rank += presence[u];
        if (presence[t]) {
            unique_out[rank] = t;
            uniq_f_out[rank] = (float)t;
        }
    }
}

// ---------------- kernel 1: per-node FFNs (key & value), logits ----------------
// grid = N*L blocks, 512 threads = 8 waves; wave = (path p, head h)
__global__ __launch_bounds__(512) void k_ffn(
    const float* __restrict__ feat, const float* __restrict__ query,
    const float* __restrict__ kw0, const float* __restrict__ kb0,
    const float* __restrict__ kw1, const float* __restrict__ kb1,
    const float* __restrict__ vw0, const float* __restrict__ vb0,
    const float* __restrict__ vw1, const float* __restrict__ vb1,
    const float* __restrict__ gamma, const float* __restrict__ beta,
    float* __restrict__ ws_logits, float* __restrict__ ws_value)
{
    const int m = blockIdx.x;            // (n,l) flat, 0..4095
    const int t = threadIdx.x;
    const int w = t >> 6;                // wave 0..7
    const int L = t & 63;                // lane
    const int p = w >> 2;                // 0 = key path, 1 = value path
    const int h = w & 3;                 // head

    __shared__ float h_lds[8][64];

    const size_t mh = (size_t)(m * HH + h);
    const float* w0 = (p ? vw0 : kw0) + mh * (FF * EE);   // 4096 floats
    const float* b0 = (p ? vb0 : kb0) + mh * FF;          // 64
    const float* w1 = (p ? vw1 : kw1) + mh * (FF * DD);   // 1024
    const float* b1 = (p ? vb1 : kb1) + mh * DD;          // 16

    // feat fragment: lane L covers e = 4*(L&15) .. +3
    float4 f4 = *(const float4*)(feat + (size_t)m * EE + 4 * (L & 15));

    // ---- stage 1: hvec[f] = dot(feat, w0[f,:])  (linear coalesced loads) ----
    #pragma unroll
    for (int it = 0; it < 16; ++it) {
        float4 wv = *(const float4*)(w0 + it * 256 + 4 * L);  // row r = it*4 + L/16
        float s = wv.x * f4.x + wv.y * f4.y + wv.z * f4.z + wv.w * f4.w;
        s += __shfl_xor(s, 1, 64);
        s += __shfl_xor(s, 2, 64);
        s += __shfl_xor(s, 4, 64);
        s += __shfl_xor(s, 8, 64);
        if ((L & 15) == 0) h_lds[w][it * 4 + (L >> 4)] = s;
    }
    __syncthreads();

    // ---- stage 2: out[d] = sum_f relu(h[f]+b0[f]) * w1[f,d] ----
    float4 acc = make_float4(0.f, 0.f, 0.f, 0.f);
    #pragma unroll
    for (int i = 0; i < 4; ++i) {
        float4 wv = *(const float4*)(w1 + i * 256 + 4 * L);   // f = i*16 + L/4, d0 = 4*(L&3)
        int f = i * 16 + (L >> 2);
        float hv = h_lds[w][f] + b0[f];
        hv = hv > 0.f ? hv : 0.f;
        acc.x += hv * wv.x; acc.y += hv * wv.y;
        acc.z += hv * wv.z; acc.w += hv * wv.w;
    }
    // reduce across the 16 lanes sharing (L&3)
    #pragma unroll
    for (int mask = 4; mask <= 32; mask <<= 1) {
        acc.x += __shfl_xor(acc.x, mask, 64);
        acc.y += __shfl_xor(acc.y, mask, 64);
        acc.z += __shfl_xor(acc.z, mask, 64);
        acc.w += __shfl_xor(acc.w, mask, 64);
    }
    const int dg = L & 3;                 // d-group: d = 4*dg .. 4*dg+3
    float4 bv = *(const float4*)(b1 + 4 * dg);
    acc.x += bv.x; acc.y += bv.y; acc.z += bv.z; acc.w += bv.w;

    // ---- LayerNorm over D=16 (key_gamma/key_beta for BOTH paths, per reference) ----
    float s = acc.x + acc.y + acc.z + acc.w;
    s += __shfl_xor(s, 1, 64);
    s += __shfl_xor(s, 2, 64);
    float mu = s * (1.f / 16.f);
    float d0 = acc.x - mu, d1 = acc.y - mu, d2 = acc.z - mu, d3 = acc.w - mu;
    float q = d0 * d0 + d1 * d1 + d2 * d2 + d3 * d3;
    q += __shfl_xor(q, 1, 64);
    q += __shfl_xor(q, 2, 64);
    float rstd = rsqrtf(q * (1.f / 16.f) + 1e-5f);
    float4 gv = *(const float4*)(gamma + 4 * dg);
    float4 be = *(const float4*)(beta + 4 * dg);
    float4 y;
    y.x = d0 * rstd * gv.x + be.x;
    y.y = d1 * rstd * gv.y + be.y;
    y.z = d2 * rstd * gv.z + be.z;
    y.w = d3 * rstd * gv.w + be.w;

    if (p == 0) {
        // logits[m,h] = dot(key, query)
        float4 qv = *(const float4*)(query + mh * DD + 4 * dg);
        float lg = y.x * qv.x + y.y * qv.y + y.z * qv.z + y.w * qv.w;
        lg += __shfl_xor(lg, 1, 64);
        lg += __shfl_xor(lg, 2, 64);
        if (L == 0) ws_logits[m * HH + h] = lg;
    } else {
        if (L < 4) *(float4*)(ws_value + mh * DD + 4 * L) = y;
    }
}

// ---------------- kernel 2: masked softmax + weighted sum + out LayerNorm ----------------
// grid = C blocks, 256 threads: thread t -> (h = t&3, g = t>>2)
__global__ __launch_bounds__(256) void k_softmax_out(
    const float* __restrict__ logits, const float* __restrict__ value,
    const int* __restrict__ comp, const int* __restrict__ unique,
    const float* __restrict__ out_gamma, const float* __restrict__ out_beta,
    float* __restrict__ out0, float* __restrict__ attn_out)
{
    const int c = blockIdx.x;
    const int t = threadIdx.x;
    const int h = t & 3;
    const int g = t >> 2;
    const int uc = unique[c];

    __shared__ float red[HH][64];
    __shared__ float accs[256][16];

    // pass 1: masked max per head
    float mx = -3.0e38f;
    for (int k = 0; k < 64; ++k) {
        int m = g + (k << 6);
        int n = m >> 1;
        float lv = logits[m * HH + h];
        float x = (comp[n] == uc) ? lv : -1e9f;
        mx = fmaxf(mx, x);
    }
    red[h][g] = mx;
    __syncthreads();
    for (int s = 32; s >= 1; s >>= 1) {
        if (g < s) red[h][g] = fmaxf(red[h][g], red[h][g + s]);
        __syncthreads();
    }
    const float maxv = red[h][0];
    __syncthreads();

    // pass 2: sum of exp
    float se = 0.f;
    for (int k = 0; k < 64; ++k) {
        int m = g + (k << 6);
        int n = m >> 1;
        float lv = logits[m * HH + h];
        float x = (comp[n] == uc) ? lv : -1e9f;
        se += expf(x - maxv);
    }
    red[h][g] = se;
    __syncthreads();
    for (int s = 32; s >= 1; s >>= 1) {
        if (g < s) red[h][g] += red[h][g + s];
        __syncthreads();
    }
    const float inv = 1.f / red[h][0];

    // pass 3: write attn, accumulate out[c,h,:]
    float4 a0 = make_float4(0.f,0.f,0.f,0.f), a1 = a0, a2 = a0, a3 = a0;
    for (int k = 0; k < 64; ++k) {
        int m = g + (k << 6);
        int n = m >> 1;
        bool mem = (comp[n] == uc);
        float lv = logits[m * HH + h];
        float x = mem ? lv : -1e9f;
        float at = expf(x - maxv) * inv;   // exactly 0 for non-members
        attn_out[(size_t)c * (ML * HH) + m * HH + h] = at;
        if (mem) {
            const float4* vp = (const float4*)(value + (size_t)(m * HH + h) * DD);
            float4 v0 = vp[0], v1 = vp[1], v2 = vp[2], v3 = vp[3];
            a0.x += at*v0.x; a0.y += at*v0.y; a0.z += at*v0.z; a0.w += at*v0.w;
            a1.x += at*v1.x; a1.y += at*v1.y; a1.z += at*v1.z; a1.w += at*v1.w;
            a2.x += at*v2.x; a2.y += at*v2.y; a2.z += at*v2.z; a2.w += at*v2.w;
            a3.x += at*v3.x; a3.y += at*v3.y; a3.z += at*v3.z; a3.w += at*v3.w;
        }
    }
    accs[t][0]=a0.x;  accs[t][1]=a0.y;  accs[t][2]=a0.z;  accs[t][3]=a0.w;
    accs[t][4]=a1.x;  accs[t][5]=a1.y;  accs[t][6]=a1.z;  accs[t][7]=a1.w;
    accs[t][8]=a2.x;  accs[t][9]=a2.y;  accs[t][10]=a2.z; accs[t][11]=a2.w;
    accs[t][12]=a3.x; accs[t][13]=a3.y; accs[t][14]=a3.z; accs[t][15]=a3.w;
    __syncthreads();
    for (int s = 32; s >= 1; s >>= 1) {
        if (g < s) {
            #pragma unroll
            for (int j = 0; j < 16; ++j) accs[t][j] += accs[t + 4 * s][j];
        }
        __syncthreads();
    }

    // final LayerNorm over D=16 per (c,h): rows 0..3 of accs hold the head sums
    if (t < 64) {
        int hh = t >> 4, d = t & 15;
        float val = accs[hh][d];
        float s = val;
        s += __shfl_xor(s, 1, 64); s += __shfl_xor(s, 2, 64);
        s += __shfl_xor(s, 4, 64); s += __shfl_xor(s, 8, 64);
        float mu = s * (1.f / 16.f);
        float dx = val - mu;
        float q = dx * dx;
        q += __shfl_xor(q, 1, 64); q += __shfl_xor(q, 2, 64);
        q += __shfl_xor(q, 4, 64); q += __shfl_xor(q, 8, 64);
        float rstd = rsqrtf(q * (1.f / 16.f) + 1e-5f);
        out0[c * 64 + t] = dx * rstd * out_gamma[d] + out_beta[d];
    }
}

extern "C" void kernel_launch(void* const* d_in, const int* in_sizes, int n_in,
                              void* d_out, int out_size, void* d_ws, size_t ws_size,
                              hipStream_t stream) {
    const float* feat      = (const float*)d_in[0];
    const float* query     = (const float*)d_in[1];
    const float* kw0       = (const float*)d_in[2];
    const float* kb0       = (const float*)d_in[3];
    const float* kw1       = (const float*)d_in[4];
    const float* kb1       = (const float*)d_in[5];
    const float* vw0       = (const float*)d_in[6];
    const float* vb0       = (const float*)d_in[7];
    const float* vw1       = (const float*)d_in[8];
    const float* vb1       = (const float*)d_in[9];
    const float* key_gamma = (const float*)d_in[10];
    const float* key_beta  = (const float*)d_in[11];
    const float* out_gamma = (const float*)d_in[12];
    const float* out_beta  = (const float*)d_in[13];
    const int*   comp      = (const int*)d_in[14];

    float* out = (float*)d_out;
    float* out0     = out;                       // (C, 64)
    float* attn_out = out + CC * 64;             // (C, N, L, H)
    float* uniq_f   = out + CC * 64 + (size_t)CC * ML * HH; // (C,)

    float* wsf       = (float*)d_ws;
    float* ws_logits = wsf;                      // 16384 floats
    float* ws_value  = wsf + ML * HH;            // 262144 floats
    int*   ws_pres   = (int*)(wsf + ML * HH + (size_t)ML * HH * DD);
    int*   ws_unique = ws_pres + 64;

    hipLaunchKernelGGL(k_unique, dim3(1), dim3(256), 0, stream,
                       comp, ws_pres, ws_unique, uniq_f);
    hipLaunchKernelGGL(k_ffn, dim3(ML), dim3(512), 0, stream,
                       feat, query, kw0, kb0, kw1, kb1, vw0, vb0, vw1, vb1,
                       key_gamma, key_beta, ws_logits, ws_value);
    hipLaunchKernelGGL(k_softmax_out, dim3(CC), dim3(256), 0, stream,
                       ws_logits, ws_value, comp, ws_unique,
                       out_gamma, out_beta, out0, attn_out);
}

// Round 2
// 610.813 us; speedup vs baseline: 1.0600x; 1.0600x over previous
//
#include <hip/hip_runtime.h>
#include <cstdint>
#include <cstddef>

#define NN 2048
#define LL 2
#define HH 4
#define DD 16
#define FF 64
#define CC 32
#define EE 64
#define ML (NN*LL)          // 4096

// ---------------- kernel 0: unique component ids + per-node rank ----------------
__global__ __launch_bounds__(256) void k_unique(const int* __restrict__ comp,
                                                int* __restrict__ rank_out,
                                                int* __restrict__ unique_out,
                                                int* __restrict__ count_out,
                                                float* __restrict__ uniq_f_out)
{
    __shared__ int pres[64];
    __shared__ int rankOf[64];
    int t = threadIdx.x;
    if (t < 64) pres[t] = 0;
    __syncthreads();
    for (int n = t; n < NN; n += 256) {
        int v = comp[n];
        if (v >= 0 && v < 64) pres[v] = 1;
    }
    __syncthreads();
    if (t < 64) {
        int rank = 0;
        for (int u = 0; u < t; ++u) rank += pres[u];
        rankOf[t] = rank;
        if (pres[t]) {
            unique_out[rank] = t;
            uniq_f_out[rank] = (float)t;
        }
        if (t == 63) count_out[0] = rank + pres[63];
    }
    __syncthreads();
    for (int n = t; n < NN; n += 256) {
        rank_out[n] = rankOf[comp[n] & 63];
    }
}

// ---------------- kernel 1: per-node FFNs (key & value), logits ----------------
// grid = N*L blocks, 512 threads = 8 waves; wave = (path p, head h)
__global__ __launch_bounds__(512) void k_ffn(
    const float* __restrict__ feat, const float* __restrict__ query,
    const float* __restrict__ kw0, const float* __restrict__ kb0,
    const float* __restrict__ kw1, const float* __restrict__ kb1,
    const float* __restrict__ vw0, const float* __restrict__ vb0,
    const float* __restrict__ vw1, const float* __restrict__ vb1,
    const float* __restrict__ gamma, const float* __restrict__ beta,
    float* __restrict__ ws_logitsT, float* __restrict__ ws_value)
{
    const int m = blockIdx.x;            // (n,l) flat, 0..4095
    const int t = threadIdx.x;
    const int w = t >> 6;                // wave 0..7
    const int L = t & 63;                // lane
    const int p = w >> 2;                // 0 = key path, 1 = value path
    const int h = w & 3;                 // head

    __shared__ float h_lds[8][64];

    const size_t mh = (size_t)(m * HH + h);
    const float* w0 = (p ? vw0 : kw0) + mh * (FF * EE);   // 4096 floats
    const float* b0 = (p ? vb0 : kb0) + mh * FF;          // 64
    const float* w1 = (p ? vw1 : kw1) + mh * (FF * DD);   // 1024
    const float* b1 = (p ? vb1 : kb1) + mh * DD;          // 16

    // feat fragment: lane L covers e = 4*(L&15) .. +3
    float4 f4 = *(const float4*)(feat + (size_t)m * EE + 4 * (L & 15));

    // ---- stage 1: hvec[f] = dot(feat, w0[f,:])  (linear coalesced loads) ----
    #pragma unroll
    for (int it = 0; it < 16; ++it) {
        float4 wv = *(const float4*)(w0 + it * 256 + 4 * L);  // row r = it*4 + L/16
        float s = wv.x * f4.x + wv.y * f4.y + wv.z * f4.z + wv.w * f4.w;
        s += __shfl_xor(s, 1, 64);
        s += __shfl_xor(s, 2, 64);
        s += __shfl_xor(s, 4, 64);
        s += __shfl_xor(s, 8, 64);
        if ((L & 15) == 0) h_lds[w][it * 4 + (L >> 4)] = s;
    }
    __syncthreads();

    // ---- stage 2: out[d] = sum_f relu(h[f]+b0[f]) * w1[f,d] ----
    float4 acc = make_float4(0.f, 0.f, 0.f, 0.f);
    #pragma unroll
    for (int i = 0; i < 4; ++i) {
        float4 wv = *(const float4*)(w1 + i * 256 + 4 * L);   // f = i*16 + L/4, d0 = 4*(L&3)
        int f = i * 16 + (L >> 2);
        float hv = h_lds[w][f] + b0[f];
        hv = hv > 0.f ? hv : 0.f;
        acc.x += hv * wv.x; acc.y += hv * wv.y;
        acc.z += hv * wv.z; acc.w += hv * wv.w;
    }
    // reduce across the 16 lanes sharing (L&3)
    #pragma unroll
    for (int mask = 4; mask <= 32; mask <<= 1) {
        acc.x += __shfl_xor(acc.x, mask, 64);
        acc.y += __shfl_xor(acc.y, mask, 64);
        acc.z += __shfl_xor(acc.z, mask, 64);
        acc.w += __shfl_xor(acc.w, mask, 64);
    }
    const int dg = L & 3;                 // d-group: d = 4*dg .. 4*dg+3
    float4 bv = *(const float4*)(b1 + 4 * dg);
    acc.x += bv.x; acc.y += bv.y; acc.z += bv.z; acc.w += bv.w;

    // ---- LayerNorm over D=16 (key_gamma/key_beta for BOTH paths, per reference) ----
    float s = acc.x + acc.y + acc.z + acc.w;
    s += __shfl_xor(s, 1, 64);
    s += __shfl_xor(s, 2, 64);
    float mu = s * (1.f / 16.f);
    float d0 = acc.x - mu, d1 = acc.y - mu, d2 = acc.z - mu, d3 = acc.w - mu;
    float q = d0 * d0 + d1 * d1 + d2 * d2 + d3 * d3;
    q += __shfl_xor(q, 1, 64);
    q += __shfl_xor(q, 2, 64);
    float rstd = rsqrtf(q * (1.f / 16.f) + 1e-5f);
    float4 gv = *(const float4*)(gamma + 4 * dg);
    float4 be = *(const float4*)(beta + 4 * dg);
    float4 y;
    y.x = d0 * rstd * gv.x + be.x;
    y.y = d1 * rstd * gv.y + be.y;
    y.z = d2 * rstd * gv.z + be.z;
    y.w = d3 * rstd * gv.w + be.w;

    if (p == 0) {
        // logits[h][m] = dot(key, query)   (transposed store for coalesced softmax reads)
        float4 qv = *(const float4*)(query + mh * DD + 4 * dg);
        float lg = y.x * qv.x + y.y * qv.y + y.z * qv.z + y.w * qv.w;
        lg += __shfl_xor(lg, 1, 64);
        lg += __shfl_xor(lg, 2, 64);
        if (L == 0) ws_logitsT[h * ML + m] = lg;
    } else {
        if (L < 4) *(float4*)(ws_value + mh * DD + 4 * L) = y;
    }
}

// ---------------- kernel 2: masked softmax + weighted sum + out LayerNorm ----------------
// grid = (C, H) blocks, 256 threads; each block owns one (component, head)
__global__ __launch_bounds__(256) void k_softmax_out(
    const float* __restrict__ logitsT, const float* __restrict__ value,
    const int* __restrict__ rank, const int* __restrict__ count,
    const float* __restrict__ out_gamma, const float* __restrict__ out_beta,
    float* __restrict__ out0, float* __restrict__ attn_out)
{
    const int c = blockIdx.x;
    const int h = blockIdx.y;
    const int t = threadIdx.x;
    const int w = t >> 6;
    const int L = t & 63;
    if (c >= count[0]) return;

    __shared__ float red[4];
    __shared__ float wacc[4][16];

    // load 16 masked logits into registers (single coalesced pass)
    float x[16];
    bool mem[16];
    #pragma unroll
    for (int i = 0; i < 16; ++i) {
        int m = t + i * 256;
        float lv = logitsT[h * ML + m];
        mem[i] = (rank[m >> 1] == c);
        x[i] = mem[i] ? lv : -1e9f;
    }

    // max
    float mx = x[0];
    #pragma unroll
    for (int i = 1; i < 16; ++i) mx = fmaxf(mx, x[i]);
    #pragma unroll
    for (int msk = 1; msk <= 32; msk <<= 1) mx = fmaxf(mx, __shfl_xor(mx, msk, 64));
    if (L == 0) red[w] = mx;
    __syncthreads();
    mx = fmaxf(fmaxf(red[0], red[1]), fmaxf(red[2], red[3]));
    __syncthreads();

    // exp + sum
    float se = 0.f;
    #pragma unroll
    for (int i = 0; i < 16; ++i) {
        x[i] = __expf(x[i] - mx) == 0.f ? expf(x[i] - mx) : expf(x[i] - mx);
        se += x[i];
    }
    #pragma unroll
    for (int msk = 1; msk <= 32; msk <<= 1) se += __shfl_xor(se, msk, 64);
    if (L == 0) red[w] = se;
    __syncthreads();
    const float inv = 1.f / (red[0] + red[1] + red[2] + red[3]);

    // attn write + value accumulate
    float acc[16];
    #pragma unroll
    for (int j = 0; j < 16; ++j) acc[j] = 0.f;
    #pragma unroll
    for (int i = 0; i < 16; ++i) {
        int m = t + i * 256;
        float at = x[i] * inv;
        attn_out[(size_t)c * (ML * HH) + (size_t)m * HH + h] = at;
        if (mem[i]) {
            const float4* vp = (const float4*)(value + (size_t)(m * HH + h) * DD);
            float4 v0 = vp[0], v1 = vp[1], v2 = vp[2], v3 = vp[3];
            acc[0]+=at*v0.x; acc[1]+=at*v0.y; acc[2]+=at*v0.z; acc[3]+=at*v0.w;
            acc[4]+=at*v1.x; acc[5]+=at*v1.y; acc[6]+=at*v1.z; acc[7]+=at*v1.w;
            acc[8]+=at*v2.x; acc[9]+=at*v2.y; acc[10]+=at*v2.z; acc[11]+=at*v2.w;
            acc[12]+=at*v3.x; acc[13]+=at*v3.y; acc[14]+=at*v3.z; acc[15]+=at*v3.w;
        }
    }
    // wave reduce each of 16 components
    #pragma unroll
    for (int j = 0; j < 16; ++j) {
        #pragma unroll
        for (int msk = 1; msk <= 32; msk <<= 1) acc[j] += __shfl_xor(acc[j], msk, 64);
    }
    if (L == 0) {
        #pragma unroll
        for (int j = 0; j < 16; ++j) wacc[w][j] = acc[j];
    }
    __syncthreads();

    // final LayerNorm over D=16 (threads 0..15, all in wave 0)
    if (t < 16) {
        float val = wacc[0][t] + wacc[1][t] + wacc[2][t] + wacc[3][t];
        float s = val;
        s += __shfl_xor(s, 1, 64); s += __shfl_xor(s, 2, 64);
        s += __shfl_xor(s, 4, 64); s += __shfl_xor(s, 8, 64);
        float mu = s * (1.f / 16.f);
        float dx = val - mu;
        float q = dx * dx;
        q += __shfl_xor(q, 1, 64); q += __shfl_xor(q, 2, 64);
        q += __shfl_xor(q, 4, 64); q += __shfl_xor(q, 8, 64);
        float rstd = rsqrtf(q * (1.f / 16.f) + 1e-5f);
        out0[c * 64 + h * 16 + t] = dx * rstd * out_gamma[t] + out_beta[t];
    }
}

extern "C" void kernel_launch(void* const* d_in, const int* in_sizes, int n_in,
                              void* d_out, int out_size, void* d_ws, size_t ws_size,
                              hipStream_t stream) {
    const float* feat      = (const float*)d_in[0];
    const float* query     = (const float*)d_in[1];
    const float* kw0       = (const float*)d_in[2];
    const float* kb0       = (const float*)d_in[3];
    const float* kw1       = (const float*)d_in[4];
    const float* kb1       = (const float*)d_in[5];
    const float* vw0       = (const float*)d_in[6];
    const float* vb0       = (const float*)d_in[7];
    const float* vw1       = (const float*)d_in[8];
    const float* vb1       = (const float*)d_in[9];
    const float* key_gamma = (const float*)d_in[10];
    const float* key_beta  = (const float*)d_in[11];
    const float* out_gamma = (const float*)d_in[12];
    const float* out_beta  = (const float*)d_in[13];
    const int*   comp      = (const int*)d_in[14];

    float* out = (float*)d_out;
    float* out0     = out;                       // (C, 64)
    float* attn_out = out + CC * 64;             // (C, N, L, H)
    float* uniq_f   = out + CC * 64 + (size_t)CC * ML * HH; // (C,)

    float* wsf        = (float*)d_ws;
    float* ws_logitsT = wsf;                     // H*ML = 16384 floats
    float* ws_value   = wsf + HH * ML;           // ML*H*D = 262144 floats
    int*   ws_rank    = (int*)(wsf + HH * ML + (size_t)ML * HH * DD);  // NN ints
    int*   ws_unique  = ws_rank + NN;            // 64 ints
    int*   ws_count   = ws_unique + 64;          // 1 int

    hipLaunchKernelGGL(k_unique, dim3(1), dim3(256), 0, stream,
                       comp, ws_rank, ws_unique, ws_count, uniq_f);
    hipLaunchKernelGGL(k_ffn, dim3(ML), dim3(512), 0, stream,
                       feat, query, kw0, kb0, kw1, kb1, vw0, vb0, vw1, vb1,
                       key_gamma, key_beta, ws_logitsT, ws_value);
    hipLaunchKernelGGL(k_softmax_out, dim3(CC, HH), dim3(256), 0, stream,
                       ws_logitsT, ws_value, ws_rank, ws_count,
                       out_gamma, out_beta, out0, attn_out);
}